// Round 7
// baseline (3783.181 us; speedup 1.0000x reference)
//
#include <hip/hip_runtime.h>

#define T_DIM 16
#define HW_DIM 4096
#define C_DIM 64
#define GN_EPS 1e-5f

__device__ __forceinline__ float leaky(float x) { return x > 0.f ? x : 0.01f * x; }

// One edge per lane. ALL per-lane arrays are indexed with compile-time
// constants only (full unroll) so they live in VGPRs, never scratch.
// Weight matrices are read at wave-uniform addresses -> s_load broadcasts.
// __launch_bounds__(256,4): 4 waves/EU min -> 16 waves/CU, VGPR cap 128
// (measured need: 100). R6's (256,1) capped occupancy at 19% and left the
// gather+atomic latency unhidden.
__global__ __launch_bounds__(256, 4) void edge_kernel(
    const float* __restrict__ gf, const float* __restrict__ pos,
    const int* __restrict__ edge, const float* __restrict__ weight,
    const float* __restrict__ W1, const float* __restrict__ b1,
    const float* __restrict__ W2, const float* __restrict__ b2,
    const float* __restrict__ gdg, const float* __restrict__ gdb,
    const float* __restrict__ Wa, const float* __restrict__ ba,
    float* __restrict__ copyb, int* __restrict__ mask, int E)
{
    int e = blockIdx.x * blockDim.x + threadIdx.x;
    if (e >= E) return;

    const int4 ev = ((const int4*)edge)[e];  // eb, et, es, ed
    const int base = (ev.x * T_DIM + ev.y) * HW_DIM;
    const long flat_pre = (long)base + ev.z;
    const long flat_suc = (long)base + HW_DIM + ev.w;

    const float2 pp = ((const float2*)pos)[ev.y * HW_DIM + ev.z];
    const float2 ps = ((const float2*)pos)[(ev.y + 1) * HW_DIM + ev.w];
    const float pd0 = ps.x - pp.x;
    const float pd1 = ps.y - pp.y;
    const float w = weight[e];

    // h = leaky_relu(pos_dist @ W1 + b1)
    float h[C_DIM];
#pragma unroll
    for (int c = 0; c < C_DIM; c++)
        h[c] = leaky(fmaf(pd0, W1[c], fmaf(pd1, W1[C_DIM + c], b1[c])));

    // d = h @ W2 + b2   (FULL unroll: h[k] is a constant-index register)
    float d[C_DIM];
#pragma unroll
    for (int c = 0; c < C_DIM; c++) d[c] = b2[c];
#pragma unroll
    for (int k = 0; k < C_DIM; k++) {
        const float hk = h[k];
#pragma unroll
        for (int c = 0; c < C_DIM; c++) d[c] = fmaf(hk, W2[k * C_DIM + c], d[c]);
    }
    // h is dead here.

    // group_norm stats of d (per-lane reduction over registers)
    float s = 0.f, sq = 0.f;
#pragma unroll
    for (int c = 0; c < C_DIM; c++) { s += d[c]; sq = fmaf(d[c], d[c], sq); }
    const float mean = s * (1.f / C_DIM);
    const float var = sq * (1.f / C_DIM) - mean * mean;
    const float rs = rsqrtf(var + GN_EPS);

    // u = value + dist_emb, in place (d -> u), value streamed as float4
    const float4* vrow = (const float4*)(gf + flat_pre * C_DIM);
#pragma unroll
    for (int q = 0; q < C_DIM / 4; q++) {
        const float4 v = vrow[q];
        d[4 * q + 0] = v.x + fmaf((d[4 * q + 0] - mean) * rs, gdg[4 * q + 0], gdb[4 * q + 0]);
        d[4 * q + 1] = v.y + fmaf((d[4 * q + 1] - mean) * rs, gdg[4 * q + 1], gdb[4 * q + 1]);
        d[4 * q + 2] = v.z + fmaf((d[4 * q + 2] - mean) * rs, gdg[4 * q + 2], gdb[4 * q + 2]);
        d[4 * q + 3] = v.w + fmaf((d[4 * q + 3] - mean) * rs, gdg[4 * q + 3], gdb[4 * q + 3]);
    }

    // att = u @ Wa + ba   (FULL unroll)
    float acc[C_DIM];
#pragma unroll
    for (int c = 0; c < C_DIM; c++) acc[c] = ba[c];
#pragma unroll
    for (int k = 0; k < C_DIM; k++) {
        const float uk = d[k];
#pragma unroll
        for (int c = 0; c < C_DIM; c++) acc[c] = fmaf(uk, Wa[k * C_DIM + c], acc[c]);
    }

    float* crow = copyb + flat_suc * C_DIM;
#pragma unroll
    for (int c = 0; c < C_DIM; c++) atomicAdd(crow + c, acc[c] * w);
    mask[flat_suc] = 1;
}

// One node per lane; copyb == d_out (in-place). K=128 GEMV split into two
// 64-deep fully-unrolled passes so only two 64-vectors are live at once:
// pass A streams the gf row from global, pass B consumes the normalized copy.
// __launch_bounds__(256,3): 12 waves/CU, VGPR cap ~170 (needs ~140).
__global__ __launch_bounds__(256, 3) void node_kernel(
    const float* __restrict__ gf, float* __restrict__ copyb,
    const int* __restrict__ mask,
    const float* __restrict__ gng, const float* __restrict__ gnb,
    const float* __restrict__ Wf, const float* __restrict__ bf,
    const float* __restrict__ gfg, const float* __restrict__ gfb, int N)
{
    int n = blockIdx.x * blockDim.x + threadIdx.x;
    if (n >= N) return;

    const float* grow = gf + (long)n * C_DIM;
    float* orow = copyb + (long)n * C_DIM;

    if (!mask[n]) {
        // out = gf
#pragma unroll
        for (int c = 0; c < C_DIM; c += 4)
            *(float4*)(orow + c) = *(const float4*)(grow + c);
        return;
    }

    // load accumulated copy row + GN stats
    float cp[C_DIM];
    float s = 0.f, sq = 0.f;
#pragma unroll
    for (int q = 0; q < C_DIM / 4; q++) {
        const float4 v = ((const float4*)orow)[q];
        cp[4 * q + 0] = v.x; cp[4 * q + 1] = v.y;
        cp[4 * q + 2] = v.z; cp[4 * q + 3] = v.w;
        s += v.x + v.y + v.z + v.w;
        sq = fmaf(v.x, v.x, fmaf(v.y, v.y, fmaf(v.z, v.z, fmaf(v.w, v.w, sq))));
    }
    float mean = s * (1.f / C_DIM);
    float var = sq * (1.f / C_DIM) - mean * mean;
    float rs = rsqrtf(var + GN_EPS);

    float d[C_DIM];
#pragma unroll
    for (int c = 0; c < C_DIM; c++) d[c] = bf[c];

    // pass A: d += gf_row @ Wf[0:64]   (gf streamed, never all live)
#pragma unroll
    for (int q = 0; q < C_DIM / 4; q++) {
        const float4 g = ((const float4*)grow)[q];
        const float gs[4] = {g.x, g.y, g.z, g.w};
#pragma unroll
        for (int j = 0; j < 4; j++) {
            const float gk = gs[j];
            const int k = 4 * q + j;
#pragma unroll
            for (int c = 0; c < C_DIM; c++)
                d[c] = fmaf(gk, Wf[k * C_DIM + c], d[c]);
        }
    }

    // pass B: d += group_norm(copy) @ Wf[64:128]
#pragma unroll
    for (int k = 0; k < C_DIM; k++) {
        const float ck = fmaf((cp[k] - mean) * rs, gng[k], gnb[k]);
#pragma unroll
        for (int c = 0; c < C_DIM; c++)
            d[c] = fmaf(ck, Wf[(C_DIM + k) * C_DIM + c], d[c]);
    }

    // final group_norm + leaky, write out
    s = 0.f; sq = 0.f;
#pragma unroll
    for (int c = 0; c < C_DIM; c++) { s += d[c]; sq = fmaf(d[c], d[c], sq); }
    mean = s * (1.f / C_DIM);
    var = sq * (1.f / C_DIM) - mean * mean;
    rs = rsqrtf(var + GN_EPS);

#pragma unroll
    for (int q = 0; q < C_DIM / 4; q++) {
        float4 o;
        o.x = leaky(fmaf((d[4 * q + 0] - mean) * rs, gfg[4 * q + 0], gfb[4 * q + 0]));
        o.y = leaky(fmaf((d[4 * q + 1] - mean) * rs, gfg[4 * q + 1], gfb[4 * q + 1]));
        o.z = leaky(fmaf((d[4 * q + 2] - mean) * rs, gfg[4 * q + 2], gfb[4 * q + 2]));
        o.w = leaky(fmaf((d[4 * q + 3] - mean) * rs, gfg[4 * q + 3], gfb[4 * q + 3]));
        ((float4*)orow)[q] = o;
    }
}

extern "C" void kernel_launch(void* const* d_in, const int* in_sizes, int n_in,
                              void* d_out, int out_size, void* d_ws, size_t ws_size,
                              hipStream_t stream) {
    const float* gf     = (const float*)d_in[0];
    const float* pos    = (const float*)d_in[1];
    const int*   edge   = (const int*)d_in[2];
    const float* weight = (const float*)d_in[3];
    const float* W1  = (const float*)d_in[4];
    const float* b1  = (const float*)d_in[5];
    const float* W2  = (const float*)d_in[6];
    const float* b2  = (const float*)d_in[7];
    const float* gdg = (const float*)d_in[8];
    const float* gdb = (const float*)d_in[9];
    const float* Wa  = (const float*)d_in[10];
    const float* ba  = (const float*)d_in[11];
    const float* gng = (const float*)d_in[12];
    const float* gnb = (const float*)d_in[13];
    const float* Wf  = (const float*)d_in[14];
    const float* bf  = (const float*)d_in[15];
    const float* gfg = (const float*)d_in[16];
    const float* gfb = (const float*)d_in[17];

    float* out = (float*)d_out;
    const int E = in_sizes[3];            // weight has E elements
    const int N = in_sizes[0] / C_DIM;    // B*T*HW

    int* mask = (int*)d_ws;               // N ints

    // d_out doubles as the `copy` scatter accumulator; zero both (re-poisoned
    // to 0xAA before every timed launch).
    hipMemsetAsync(d_out, 0, (size_t)N * C_DIM * sizeof(float), stream);
    hipMemsetAsync(mask, 0, (size_t)N * sizeof(int), stream);

    dim3 blk(256);
    edge_kernel<<<dim3((E + 255) / 256), blk, 0, stream>>>(
        gf, pos, edge, weight, W1, b1, W2, b2, gdg, gdb, Wa, ba, out, mask, E);
    node_kernel<<<dim3((N + 255) / 256), blk, 0, stream>>>(
        gf, out, mask, gng, gnb, Wf, bf, gfg, gfb, N);
}

// Round 9
// 1550.734 us; speedup vs baseline: 2.4396x; 2.4396x over previous
//
#include <hip/hip_runtime.h>

#define B_DIM 4
#define T_DIM 16
#define HW_DIM 4096
#define C_DIM 64
#define GN_EPS 1e-5f
#define CAP 32
#define NSUC (B_DIM * (T_DIM - 1) * HW_DIM)  // 245760 possible successor nodes

__device__ __forceinline__ float leaky(float x) { return x > 0.f ? x : 0.01f * x; }

// ---------------- CSR path (no fp32 atomics) ----------------

// One int atomic per edge: bucket edge ids by successor node (compact index).
__global__ __launch_bounds__(256, 4) void bin_kernel(
    const int* __restrict__ edge, int* __restrict__ cnt, int* __restrict__ bidx, int E)
{
    int e = blockIdx.x * blockDim.x + threadIdx.x;
    if (e >= E) return;
    const int4 ev = ((const int4*)edge)[e];          // eb, et, es, ed ; et in [0,14]
    const int sc = (ev.x * (T_DIM - 1) + ev.y) * HW_DIM + ev.w;
    const int slot = atomicAdd(&cnt[sc], 1);
    if (slot < CAP) bidx[(long)sc * CAP + slot] = e; // P(overflow) ~1e-13 at lambda=4.07
}

// One node per lane. Pull-style: recompute each incident edge's dist_emb
// (h generated on the fly: only d[64]+uacc[64] big arrays live), gather
// gf[pre], and exploit linearity: copy = (sum w*u) @ Wa + (sum w) * ba.
// Then the whole node tail (GN, concat GEMV Wf, GN, leaky) fused in regs.
__global__ __launch_bounds__(256, 3) void node_csr_kernel(
    const float* __restrict__ gf, const float* __restrict__ pos,
    const int* __restrict__ edge, const float* __restrict__ weight,
    const float* __restrict__ W1, const float* __restrict__ b1,
    const float* __restrict__ W2, const float* __restrict__ b2,
    const float* __restrict__ gdg, const float* __restrict__ gdb,
    const float* __restrict__ Wa, const float* __restrict__ ba,
    const float* __restrict__ gng, const float* __restrict__ gnb,
    const float* __restrict__ Wf, const float* __restrict__ bf,
    const float* __restrict__ gfg, const float* __restrict__ gfb,
    const int* __restrict__ cnt, const int* __restrict__ bidx,
    float* __restrict__ out, int N)
{
    int n = blockIdx.x * blockDim.x + threadIdx.x;
    if (n >= N) return;
    const float* grow = gf + (long)n * C_DIM;
    float* orow = out + (long)n * C_DIM;

    const int t = (n >> 12) & (T_DIM - 1);   // n = (b*T + t)*HW + s, HW=2^12
    int k = 0, sc = 0;
    if (t > 0) {
        const int b = n >> 16;               // T*HW = 2^16
        sc = n - (b + 1) * HW_DIM;           // compact successor index
        k = cnt[sc];
    }
    if (k == 0) {                            // unmasked: out = gf
#pragma unroll
        for (int q = 0; q < C_DIM / 4; q++)
            ((float4*)orow)[q] = ((const float4*)grow)[q];
        return;
    }
    if (k > CAP) k = CAP;

    float uacc[C_DIM];
#pragma unroll
    for (int c = 0; c < C_DIM; c++) uacc[c] = 0.f;
    float sw = 0.f;

    for (int j = 0; j < k; j++) {
        const int e = bidx[(long)sc * CAP + j];
        const int4 ev = ((const int4*)edge)[e];
        const float w = weight[e];
        const float2 pp = ((const float2*)pos)[ev.y * HW_DIM + ev.z];
        const float2 ps = ((const float2*)pos)[(ev.y + 1) * HW_DIM + ev.w];
        const float pd0 = ps.x - pp.x;
        const float pd1 = ps.y - pp.y;

        // d = h @ W2 + b2, with h[kk] generated on the fly (W1/b1 are s_loads)
        float d[C_DIM];
#pragma unroll
        for (int c = 0; c < C_DIM; c++) d[c] = b2[c];
#pragma unroll
        for (int kk = 0; kk < C_DIM; kk++) {
            const float hv = leaky(fmaf(pd0, W1[kk], fmaf(pd1, W1[C_DIM + kk], b1[kk])));
#pragma unroll
            for (int c = 0; c < C_DIM; c++) d[c] = fmaf(hv, W2[kk * C_DIM + c], d[c]);
        }
        float s = 0.f, sq = 0.f;
#pragma unroll
        for (int c = 0; c < C_DIM; c++) { s += d[c]; sq = fmaf(d[c], d[c], sq); }
        const float mean = s * (1.f / C_DIM);
        const float var = sq * (1.f / C_DIM) - mean * mean;
        const float rs = rsqrtf(var + GN_EPS);

        // uacc += w * (gf[pre] + GN(d))   (value row streamed as float4)
        const long fp = ((long)(ev.x * T_DIM + ev.y) * HW_DIM + ev.z) * C_DIM;
        const float4* vr = (const float4*)(gf + fp);
#pragma unroll
        for (int q = 0; q < C_DIM / 4; q++) {
            const float4 v = vr[q];
            uacc[4*q+0] = fmaf(w, v.x + fmaf((d[4*q+0] - mean) * rs, gdg[4*q+0], gdb[4*q+0]), uacc[4*q+0]);
            uacc[4*q+1] = fmaf(w, v.y + fmaf((d[4*q+1] - mean) * rs, gdg[4*q+1], gdb[4*q+1]), uacc[4*q+1]);
            uacc[4*q+2] = fmaf(w, v.z + fmaf((d[4*q+2] - mean) * rs, gdg[4*q+2], gdb[4*q+2]), uacc[4*q+2]);
            uacc[4*q+3] = fmaf(w, v.w + fmaf((d[4*q+3] - mean) * rs, gdg[4*q+3], gdb[4*q+3]), uacc[4*q+3]);
        }
        sw += w;
    }

    // copy row = uacc @ Wa + sw * ba   (linearity: one Wa GEMV per node)
    float c2[C_DIM];
#pragma unroll
    for (int c = 0; c < C_DIM; c++) c2[c] = sw * ba[c];
#pragma unroll
    for (int kk = 0; kk < C_DIM; kk++) {
        const float uk = uacc[kk];
#pragma unroll
        for (int c = 0; c < C_DIM; c++) c2[c] = fmaf(uk, Wa[kk * C_DIM + c], c2[c]);
    }

    // GN(copy) in place
    {
        float s = 0.f, sq = 0.f;
#pragma unroll
        for (int c = 0; c < C_DIM; c++) { s += c2[c]; sq = fmaf(c2[c], c2[c], sq); }
        const float mean = s * (1.f / C_DIM);
        const float var = sq * (1.f / C_DIM) - mean * mean;
        const float rs = rsqrtf(var + GN_EPS);
#pragma unroll
        for (int c = 0; c < C_DIM; c++)
            c2[c] = fmaf((c2[c] - mean) * rs, gng[c], gnb[c]);
    }

    // d2 = bf + grow @ Wf[0:64] + c2 @ Wf[64:128]   (reuse uacc as d2)
#pragma unroll
    for (int c = 0; c < C_DIM; c++) uacc[c] = bf[c];
#pragma unroll
    for (int q = 0; q < C_DIM / 4; q++) {
        const float4 g = ((const float4*)grow)[q];
        const float gs[4] = {g.x, g.y, g.z, g.w};
#pragma unroll
        for (int jj = 0; jj < 4; jj++) {
            const float gk = gs[jj];
            const int kk = 4 * q + jj;
#pragma unroll
            for (int c = 0; c < C_DIM; c++)
                uacc[c] = fmaf(gk, Wf[kk * C_DIM + c], uacc[c]);
        }
    }
#pragma unroll
    for (int kk = 0; kk < C_DIM; kk++) {
        const float ck = c2[kk];
#pragma unroll
        for (int c = 0; c < C_DIM; c++)
            uacc[c] = fmaf(ck, Wf[(C_DIM + kk) * C_DIM + c], uacc[c]);
    }

    // final GN + leaky -> out
    {
        float s = 0.f, sq = 0.f;
#pragma unroll
        for (int c = 0; c < C_DIM; c++) { s += uacc[c]; sq = fmaf(uacc[c], uacc[c], sq); }
        const float mean = s * (1.f / C_DIM);
        const float var = sq * (1.f / C_DIM) - mean * mean;
        const float rs = rsqrtf(var + GN_EPS);
#pragma unroll
        for (int q = 0; q < C_DIM / 4; q++) {
            float4 o;
            o.x = leaky(fmaf((uacc[4*q+0] - mean) * rs, gfg[4*q+0], gfb[4*q+0]));
            o.y = leaky(fmaf((uacc[4*q+1] - mean) * rs, gfg[4*q+1], gfb[4*q+1]));
            o.z = leaky(fmaf((uacc[4*q+2] - mean) * rs, gfg[4*q+2], gfb[4*q+2]));
            o.w = leaky(fmaf((uacc[4*q+3] - mean) * rs, gfg[4*q+3], gfb[4*q+3]));
            ((float4*)orow)[q] = o;
        }
    }
}

// ---------------- fallback path (R7 kernels, used only if ws too small) ----------------

__global__ __launch_bounds__(256, 4) void edge_kernel(
    const float* __restrict__ gf, const float* __restrict__ pos,
    const int* __restrict__ edge, const float* __restrict__ weight,
    const float* __restrict__ W1, const float* __restrict__ b1,
    const float* __restrict__ W2, const float* __restrict__ b2,
    const float* __restrict__ gdg, const float* __restrict__ gdb,
    const float* __restrict__ Wa, const float* __restrict__ ba,
    float* __restrict__ copyb, int* __restrict__ mask, int E)
{
    int e = blockIdx.x * blockDim.x + threadIdx.x;
    if (e >= E) return;
    const int4 ev = ((const int4*)edge)[e];
    const int base = (ev.x * T_DIM + ev.y) * HW_DIM;
    const long flat_pre = (long)base + ev.z;
    const long flat_suc = (long)base + HW_DIM + ev.w;
    const float2 pp = ((const float2*)pos)[ev.y * HW_DIM + ev.z];
    const float2 ps = ((const float2*)pos)[(ev.y + 1) * HW_DIM + ev.w];
    const float pd0 = ps.x - pp.x, pd1 = ps.y - pp.y;
    const float w = weight[e];
    float d[C_DIM];
#pragma unroll
    for (int c = 0; c < C_DIM; c++) d[c] = b2[c];
#pragma unroll
    for (int kk = 0; kk < C_DIM; kk++) {
        const float hv = leaky(fmaf(pd0, W1[kk], fmaf(pd1, W1[C_DIM + kk], b1[kk])));
#pragma unroll
        for (int c = 0; c < C_DIM; c++) d[c] = fmaf(hv, W2[kk * C_DIM + c], d[c]);
    }
    float s = 0.f, sq = 0.f;
#pragma unroll
    for (int c = 0; c < C_DIM; c++) { s += d[c]; sq = fmaf(d[c], d[c], sq); }
    const float mean = s * (1.f / C_DIM);
    const float var = sq * (1.f / C_DIM) - mean * mean;
    const float rs = rsqrtf(var + GN_EPS);
    const float4* vrow = (const float4*)(gf + flat_pre * C_DIM);
#pragma unroll
    for (int q = 0; q < C_DIM / 4; q++) {
        const float4 v = vrow[q];
        d[4*q+0] = v.x + fmaf((d[4*q+0] - mean) * rs, gdg[4*q+0], gdb[4*q+0]);
        d[4*q+1] = v.y + fmaf((d[4*q+1] - mean) * rs, gdg[4*q+1], gdb[4*q+1]);
        d[4*q+2] = v.z + fmaf((d[4*q+2] - mean) * rs, gdg[4*q+2], gdb[4*q+2]);
        d[4*q+3] = v.w + fmaf((d[4*q+3] - mean) * rs, gdg[4*q+3], gdb[4*q+3]);
    }
    float acc[C_DIM];
#pragma unroll
    for (int c = 0; c < C_DIM; c++) acc[c] = ba[c];
#pragma unroll
    for (int kk = 0; kk < C_DIM; kk++) {
        const float uk = d[kk];
#pragma unroll
        for (int c = 0; c < C_DIM; c++) acc[c] = fmaf(uk, Wa[kk * C_DIM + c], acc[c]);
    }
    float* crow = copyb + flat_suc * C_DIM;
#pragma unroll
    for (int c = 0; c < C_DIM; c++) atomicAdd(crow + c, acc[c] * w);
    mask[flat_suc] = 1;
}

__global__ __launch_bounds__(256, 3) void node_kernel(
    const float* __restrict__ gf, float* __restrict__ copyb,
    const int* __restrict__ mask,
    const float* __restrict__ gng, const float* __restrict__ gnb,
    const float* __restrict__ Wf, const float* __restrict__ bf,
    const float* __restrict__ gfg, const float* __restrict__ gfb, int N)
{
    int n = blockIdx.x * blockDim.x + threadIdx.x;
    if (n >= N) return;
    const float* grow = gf + (long)n * C_DIM;
    float* orow = copyb + (long)n * C_DIM;
    if (!mask[n]) {
#pragma unroll
        for (int c = 0; c < C_DIM; c += 4)
            *(float4*)(orow + c) = *(const float4*)(grow + c);
        return;
    }
    float cp[C_DIM];
    float s = 0.f, sq = 0.f;
#pragma unroll
    for (int q = 0; q < C_DIM / 4; q++) {
        const float4 v = ((const float4*)orow)[q];
        cp[4*q+0] = v.x; cp[4*q+1] = v.y; cp[4*q+2] = v.z; cp[4*q+3] = v.w;
        s += v.x + v.y + v.z + v.w;
        sq = fmaf(v.x, v.x, fmaf(v.y, v.y, fmaf(v.z, v.z, fmaf(v.w, v.w, sq))));
    }
    float mean = s * (1.f / C_DIM);
    float var = sq * (1.f / C_DIM) - mean * mean;
    float rs = rsqrtf(var + GN_EPS);
    float d[C_DIM];
#pragma unroll
    for (int c = 0; c < C_DIM; c++) d[c] = bf[c];
#pragma unroll
    for (int q = 0; q < C_DIM / 4; q++) {
        const float4 g = ((const float4*)grow)[q];
        const float gs[4] = {g.x, g.y, g.z, g.w};
#pragma unroll
        for (int jj = 0; jj < 4; jj++) {
            const float gk = gs[jj];
            const int kk = 4 * q + jj;
#pragma unroll
            for (int c = 0; c < C_DIM; c++) d[c] = fmaf(gk, Wf[kk * C_DIM + c], d[c]);
        }
    }
#pragma unroll
    for (int kk = 0; kk < C_DIM; kk++) {
        const float ck = fmaf((cp[kk] - mean) * rs, gng[kk], gnb[kk]);
#pragma unroll
        for (int c = 0; c < C_DIM; c++) d[c] = fmaf(ck, Wf[(C_DIM + kk) * C_DIM + c], d[c]);
    }
    s = 0.f; sq = 0.f;
#pragma unroll
    for (int c = 0; c < C_DIM; c++) { s += d[c]; sq = fmaf(d[c], d[c], sq); }
    mean = s * (1.f / C_DIM);
    var = sq * (1.f / C_DIM) - mean * mean;
    rs = rsqrtf(var + GN_EPS);
#pragma unroll
    for (int q = 0; q < C_DIM / 4; q++) {
        float4 o;
        o.x = leaky(fmaf((d[4*q+0] - mean) * rs, gfg[4*q+0], gfb[4*q+0]));
        o.y = leaky(fmaf((d[4*q+1] - mean) * rs, gfg[4*q+1], gfb[4*q+1]));
        o.z = leaky(fmaf((d[4*q+2] - mean) * rs, gfg[4*q+2], gfb[4*q+2]));
        o.w = leaky(fmaf((d[4*q+3] - mean) * rs, gfg[4*q+3], gfb[4*q+3]));
        ((float4*)orow)[q] = o;
    }
}

extern "C" void kernel_launch(void* const* d_in, const int* in_sizes, int n_in,
                              void* d_out, int out_size, void* d_ws, size_t ws_size,
                              hipStream_t stream) {
    const float* gf     = (const float*)d_in[0];
    const float* pos    = (const float*)d_in[1];
    const int*   edge   = (const int*)d_in[2];
    const float* weight = (const float*)d_in[3];
    const float* W1  = (const float*)d_in[4];
    const float* b1  = (const float*)d_in[5];
    const float* W2  = (const float*)d_in[6];
    const float* b2  = (const float*)d_in[7];
    const float* gdg = (const float*)d_in[8];
    const float* gdb = (const float*)d_in[9];
    const float* Wa  = (const float*)d_in[10];
    const float* ba  = (const float*)d_in[11];
    const float* gng = (const float*)d_in[12];
    const float* gnb = (const float*)d_in[13];
    const float* Wf  = (const float*)d_in[14];
    const float* bf  = (const float*)d_in[15];
    const float* gfg = (const float*)d_in[16];
    const float* gfb = (const float*)d_in[17];

    float* out = (float*)d_out;
    const int E = in_sizes[3];
    const int N = in_sizes[0] / C_DIM;

    const size_t cnt_bytes  = (size_t)NSUC * sizeof(int);
    const size_t bidx_bytes = (size_t)NSUC * CAP * sizeof(int);
    dim3 blk(256);

    if (ws_size >= cnt_bytes + bidx_bytes) {
        int* cnt  = (int*)d_ws;
        int* bidx = cnt + NSUC;
        hipMemsetAsync(cnt, 0, cnt_bytes, stream);
        bin_kernel<<<dim3((E + 255) / 256), blk, 0, stream>>>(edge, cnt, bidx, E);
        node_csr_kernel<<<dim3((N + 255) / 256), blk, 0, stream>>>(
            gf, pos, edge, weight, W1, b1, W2, b2, gdg, gdb, Wa, ba,
            gng, gnb, Wf, bf, gfg, gfb, cnt, bidx, out, N);
    } else {
        // fallback: atomic-scatter path (R7)
        int* mask = (int*)d_ws;
        hipMemsetAsync(d_out, 0, (size_t)N * C_DIM * sizeof(float), stream);
        hipMemsetAsync(mask, 0, (size_t)N * sizeof(int), stream);
        edge_kernel<<<dim3((E + 255) / 256), blk, 0, stream>>>(
            gf, pos, edge, weight, W1, b1, W2, b2, gdg, gdb, Wa, ba, out, mask, E);
        node_kernel<<<dim3((N + 255) / 256), blk, 0, stream>>>(
            gf, out, mask, gng, gnb, Wf, bf, gfg, gfb, N);
    }
}

// Round 12
// 1244.550 us; speedup vs baseline: 3.0398x; 1.2460x over previous
//
#include <hip/hip_runtime.h>

#define B_DIM 4
#define T_DIM 16
#define HW_DIM 4096
#define C_DIM 64
#define GN_EPS 1e-5f
#define CAP 32
#define NSUC (B_DIM * (T_DIM - 1) * HW_DIM)  // 245760 possible successor nodes

__device__ __forceinline__ float leaky(float x) { return x > 0.f ? x : 0.01f * x; }

// ---------------- Kernel 1: fused CSR binning + per-edge GN stats ----------------
// Edge-per-lane, perfectly balanced. The 64x64 W2 GEMV runs here (no exec-mask
// waste) and only {mean, rs} (8 B) is materialized per edge. One int atomic/edge.
__global__ __launch_bounds__(256, 3) void bin_stats_kernel(
    const int* __restrict__ edge, const float* __restrict__ pos,
    const float* __restrict__ W1, const float* __restrict__ b1,
    const float* __restrict__ W2, const float* __restrict__ b2,
    int* __restrict__ cnt, int* __restrict__ bidx, float2* __restrict__ stats, int E)
{
    int e = blockIdx.x * blockDim.x + threadIdx.x;
    if (e >= E) return;
    const int4 ev = ((const int4*)edge)[e];          // eb, et, es, ed ; et in [0,14]

    const int sc = (ev.x * (T_DIM - 1) + ev.y) * HW_DIM + ev.w;
    const int slot = atomicAdd(&cnt[sc], 1);
    if (slot < CAP) bidx[(long)sc * CAP + slot] = e;

    const float2 pp = ((const float2*)pos)[ev.y * HW_DIM + ev.z];
    const float2 ps = ((const float2*)pos)[(ev.y + 1) * HW_DIM + ev.w];
    const float pd0 = ps.x - pp.x;
    const float pd1 = ps.y - pp.y;

    // h = leaky(pd @ W1 + b1)
    float h[C_DIM];
#pragma unroll
    for (int c = 0; c < C_DIM; c++)
        h[c] = leaky(fmaf(pd0, W1[c], fmaf(pd1, W1[C_DIM + c], b1[c])));

    // d = h @ W2 + b2 (full unroll; W2 rows are wave-uniform s_loads)
    float d[C_DIM];
#pragma unroll
    for (int c = 0; c < C_DIM; c++) d[c] = b2[c];
#pragma unroll
    for (int kk = 0; kk < C_DIM; kk++) {
        const float hk = h[kk];
#pragma unroll
        for (int c = 0; c < C_DIM; c++) d[c] = fmaf(hk, W2[kk * C_DIM + c], d[c]);
    }

    float s = 0.f, sq = 0.f;
#pragma unroll
    for (int c = 0; c < C_DIM; c++) { s += d[c]; sq = fmaf(d[c], d[c], sq); }
    const float mean = s * (1.f / C_DIM);
    const float var = sq * (1.f / C_DIM) - mean * mean;
    stats[e] = make_float2(mean, rsqrtf(var + GN_EPS));
}

// ---------------- Kernel 2: pull-style node kernel with GN-linearity ----------------
// Per incident edge only cheap work stays in the divergent loop:
//   hacc += (w*rs) * h_e ; vacc += w * gf[pre] ; srs,srm,sw scalars.
// GN-linearity: sum_e w*GN(d_e) = gdg*( (hacc@W2) + srs*b2 - srm ) + sw*gdb,
// so the W2 GEMV happens ONCE per node in the balanced tail.
__global__ __launch_bounds__(256, 3) void node_lin_kernel(
    const float* __restrict__ gf, const float* __restrict__ pos,
    const int* __restrict__ edge, const float* __restrict__ weight,
    const float* __restrict__ W1, const float* __restrict__ b1,
    const float* __restrict__ W2, const float* __restrict__ b2,
    const float* __restrict__ gdg, const float* __restrict__ gdb,
    const float* __restrict__ Wa, const float* __restrict__ ba,
    const float* __restrict__ gng, const float* __restrict__ gnb,
    const float* __restrict__ Wf, const float* __restrict__ bf,
    const float* __restrict__ gfg, const float* __restrict__ gfb,
    const int* __restrict__ cnt, const int* __restrict__ bidx,
    const float2* __restrict__ stats,
    float* __restrict__ out, int N)
{
    int n = blockIdx.x * blockDim.x + threadIdx.x;
    if (n >= N) return;
    const float* grow = gf + (long)n * C_DIM;
    float* orow = out + (long)n * C_DIM;

    const int t = (n >> 12) & (T_DIM - 1);   // n = (b*T + t)*HW + s, HW=2^12
    int k = 0, sc = 0;
    if (t > 0) {
        const int b = n >> 16;               // T*HW = 2^16
        sc = n - (b + 1) * HW_DIM;           // compact successor index
        k = cnt[sc];
    }
    if (k == 0) {                            // unmasked: out = gf
#pragma unroll
        for (int q = 0; q < C_DIM / 4; q++)
            ((float4*)orow)[q] = ((const float4*)grow)[q];
        return;
    }
    if (k > CAP) k = CAP;

    float hacc[C_DIM], vacc[C_DIM];
#pragma unroll
    for (int c = 0; c < C_DIM; c++) { hacc[c] = 0.f; vacc[c] = 0.f; }
    float sw = 0.f, srs = 0.f, srm = 0.f;

    for (int j = 0; j < k; j++) {
        const int e = bidx[(long)sc * CAP + j];
        const int4 ev = ((const int4*)edge)[e];
        const float w = weight[e];
        const float2 st = stats[e];          // {mean, rs}
        const float wrs = w * st.y;
        srs += wrs;
        srm += wrs * st.x;
        sw  += w;

        const float2 pp = ((const float2*)pos)[ev.y * HW_DIM + ev.z];
        const float2 ps = ((const float2*)pos)[(ev.y + 1) * HW_DIM + ev.w];
        const float pd0 = ps.x - pp.x;
        const float pd1 = ps.y - pp.y;

        // hacc += wrs * h_e (h regenerated: ~5 inst/channel, no GEMV here)
#pragma unroll
        for (int c = 0; c < C_DIM; c++) {
            const float hv = leaky(fmaf(pd0, W1[c], fmaf(pd1, W1[C_DIM + c], b1[c])));
            hacc[c] = fmaf(wrs, hv, hacc[c]);
        }

        // vacc += w * gf[pre]
        const long fp = ((long)(ev.x * T_DIM + ev.y) * HW_DIM + ev.z) * C_DIM;
        const float4* vr = (const float4*)(gf + fp);
#pragma unroll
        for (int q = 0; q < C_DIM / 4; q++) {
            const float4 v = vr[q];
            vacc[4*q+0] = fmaf(w, v.x, vacc[4*q+0]);
            vacc[4*q+1] = fmaf(w, v.y, vacc[4*q+1]);
            vacc[4*q+2] = fmaf(w, v.z, vacc[4*q+2]);
            vacc[4*q+3] = fmaf(w, v.w, vacc[4*q+3]);
        }
    }

    // t1 = hacc @ W2 (ONE GEMV per node); then fold the GN-affine terms.
    float t1[C_DIM];
#pragma unroll
    for (int c = 0; c < C_DIM; c++) t1[c] = 0.f;
#pragma unroll
    for (int kk = 0; kk < C_DIM; kk++) {
        const float hk = hacc[kk];
#pragma unroll
        for (int c = 0; c < C_DIM; c++) t1[c] = fmaf(hk, W2[kk * C_DIM + c], t1[c]);
    }
    // uaccS[c] = vacc + gdg*(t1 + srs*b2 - srm) + sw*gdb   (reuse hacc)
#pragma unroll
    for (int c = 0; c < C_DIM; c++)
        hacc[c] = fmaf(gdg[c], fmaf(srs, b2[c], t1[c] - srm), fmaf(sw, gdb[c], vacc[c]));

    // copy row = uaccS @ Wa + sw * ba   (reuse t1 as c2)
#pragma unroll
    for (int c = 0; c < C_DIM; c++) t1[c] = sw * ba[c];
#pragma unroll
    for (int kk = 0; kk < C_DIM; kk++) {
        const float uk = hacc[kk];
#pragma unroll
        for (int c = 0; c < C_DIM; c++) t1[c] = fmaf(uk, Wa[kk * C_DIM + c], t1[c]);
    }

    // GN(copy) in place
    {
        float s = 0.f, sq = 0.f;
#pragma unroll
        for (int c = 0; c < C_DIM; c++) { s += t1[c]; sq = fmaf(t1[c], t1[c], sq); }
        const float mean = s * (1.f / C_DIM);
        const float var = sq * (1.f / C_DIM) - mean * mean;
        const float rs = rsqrtf(var + GN_EPS);
#pragma unroll
        for (int c = 0; c < C_DIM; c++)
            t1[c] = fmaf((t1[c] - mean) * rs, gng[c], gnb[c]);
    }

    // d2 = bf + grow @ Wf[0:64] + t1 @ Wf[64:128]   (reuse hacc as d2)
#pragma unroll
    for (int c = 0; c < C_DIM; c++) hacc[c] = bf[c];
#pragma unroll
    for (int q = 0; q < C_DIM / 4; q++) {
        const float4 g = ((const float4*)grow)[q];
        const float gs[4] = {g.x, g.y, g.z, g.w};
#pragma unroll
        for (int jj = 0; jj < 4; jj++) {
            const float gk = gs[jj];
            const int kk = 4 * q + jj;
#pragma unroll
            for (int c = 0; c < C_DIM; c++)
                hacc[c] = fmaf(gk, Wf[kk * C_DIM + c], hacc[c]);
        }
    }
#pragma unroll
    for (int kk = 0; kk < C_DIM; kk++) {
        const float ck = t1[kk];
#pragma unroll
        for (int c = 0; c < C_DIM; c++)
            hacc[c] = fmaf(ck, Wf[(C_DIM + kk) * C_DIM + c], hacc[c]);
    }

    // final GN + leaky -> out
    {
        float s = 0.f, sq = 0.f;
#pragma unroll
        for (int c = 0; c < C_DIM; c++) { s += hacc[c]; sq = fmaf(hacc[c], hacc[c], sq); }
        const float mean = s * (1.f / C_DIM);
        const float var = sq * (1.f / C_DIM) - mean * mean;
        const float rs = rsqrtf(var + GN_EPS);
#pragma unroll
        for (int q = 0; q < C_DIM / 4; q++) {
            float4 o;
            o.x = leaky(fmaf((hacc[4*q+0] - mean) * rs, gfg[4*q+0], gfb[4*q+0]));
            o.y = leaky(fmaf((hacc[4*q+1] - mean) * rs, gfg[4*q+1], gfb[4*q+1]));
            o.z = leaky(fmaf((hacc[4*q+2] - mean) * rs, gfg[4*q+2], gfb[4*q+2]));
            o.w = leaky(fmaf((hacc[4*q+3] - mean) * rs, gfg[4*q+3], gfb[4*q+3]));
            ((float4*)orow)[q] = o;
        }
    }
}

// ---------------- fallback: R9 CSR kernels (ws too small for stats buffer) ----------------

__global__ __launch_bounds__(256, 4) void bin_kernel(
    const int* __restrict__ edge, int* __restrict__ cnt, int* __restrict__ bidx, int E)
{
    int e = blockIdx.x * blockDim.x + threadIdx.x;
    if (e >= E) return;
    const int4 ev = ((const int4*)edge)[e];
    const int sc = (ev.x * (T_DIM - 1) + ev.y) * HW_DIM + ev.w;
    const int slot = atomicAdd(&cnt[sc], 1);
    if (slot < CAP) bidx[(long)sc * CAP + slot] = e;
}

__global__ __launch_bounds__(256, 3) void node_csr_kernel(
    const float* __restrict__ gf, const float* __restrict__ pos,
    const int* __restrict__ edge, const float* __restrict__ weight,
    const float* __restrict__ W1, const float* __restrict__ b1,
    const float* __restrict__ W2, const float* __restrict__ b2,
    const float* __restrict__ gdg, const float* __restrict__ gdb,
    const float* __restrict__ Wa, const float* __restrict__ ba,
    const float* __restrict__ gng, const float* __restrict__ gnb,
    const float* __restrict__ Wf, const float* __restrict__ bf,
    const float* __restrict__ gfg, const float* __restrict__ gfb,
    const int* __restrict__ cnt, const int* __restrict__ bidx,
    float* __restrict__ out, int N)
{
    int n = blockIdx.x * blockDim.x + threadIdx.x;
    if (n >= N) return;
    const float* grow = gf + (long)n * C_DIM;
    float* orow = out + (long)n * C_DIM;
    const int t = (n >> 12) & (T_DIM - 1);
    int k = 0, sc = 0;
    if (t > 0) {
        const int b = n >> 16;
        sc = n - (b + 1) * HW_DIM;
        k = cnt[sc];
    }
    if (k == 0) {
#pragma unroll
        for (int q = 0; q < C_DIM / 4; q++)
            ((float4*)orow)[q] = ((const float4*)grow)[q];
        return;
    }
    if (k > CAP) k = CAP;
    float uacc[C_DIM];
#pragma unroll
    for (int c = 0; c < C_DIM; c++) uacc[c] = 0.f;
    float sw = 0.f;
    for (int j = 0; j < k; j++) {
        const int e = bidx[(long)sc * CAP + j];
        const int4 ev = ((const int4*)edge)[e];
        const float w = weight[e];
        const float2 pp = ((const float2*)pos)[ev.y * HW_DIM + ev.z];
        const float2 ps = ((const float2*)pos)[(ev.y + 1) * HW_DIM + ev.w];
        const float pd0 = ps.x - pp.x;
        const float pd1 = ps.y - pp.y;
        float d[C_DIM];
#pragma unroll
        for (int c = 0; c < C_DIM; c++) d[c] = b2[c];
#pragma unroll
        for (int kk = 0; kk < C_DIM; kk++) {
            const float hv = leaky(fmaf(pd0, W1[kk], fmaf(pd1, W1[C_DIM + kk], b1[kk])));
#pragma unroll
            for (int c = 0; c < C_DIM; c++) d[c] = fmaf(hv, W2[kk * C_DIM + c], d[c]);
        }
        float s = 0.f, sq = 0.f;
#pragma unroll
        for (int c = 0; c < C_DIM; c++) { s += d[c]; sq = fmaf(d[c], d[c], sq); }
        const float mean = s * (1.f / C_DIM);
        const float var = sq * (1.f / C_DIM) - mean * mean;
        const float rs = rsqrtf(var + GN_EPS);
        const long fp = ((long)(ev.x * T_DIM + ev.y) * HW_DIM + ev.z) * C_DIM;
        const float4* vr = (const float4*)(gf + fp);
#pragma unroll
        for (int q = 0; q < C_DIM / 4; q++) {
            const float4 v = vr[q];
            uacc[4*q+0] = fmaf(w, v.x + fmaf((d[4*q+0] - mean) * rs, gdg[4*q+0], gdb[4*q+0]), uacc[4*q+0]);
            uacc[4*q+1] = fmaf(w, v.y + fmaf((d[4*q+1] - mean) * rs, gdg[4*q+1], gdb[4*q+1]), uacc[4*q+1]);
            uacc[4*q+2] = fmaf(w, v.z + fmaf((d[4*q+2] - mean) * rs, gdg[4*q+2], gdb[4*q+2]), uacc[4*q+2]);
            uacc[4*q+3] = fmaf(w, v.w + fmaf((d[4*q+3] - mean) * rs, gdg[4*q+3], gdb[4*q+3]), uacc[4*q+3]);
        }
        sw += w;
    }
    float c2[C_DIM];
#pragma unroll
    for (int c = 0; c < C_DIM; c++) c2[c] = sw * ba[c];
#pragma unroll
    for (int kk = 0; kk < C_DIM; kk++) {
        const float uk = uacc[kk];
#pragma unroll
        for (int c = 0; c < C_DIM; c++) c2[c] = fmaf(uk, Wa[kk * C_DIM + c], c2[c]);
    }
    {
        float s = 0.f, sq = 0.f;
#pragma unroll
        for (int c = 0; c < C_DIM; c++) { s += c2[c]; sq = fmaf(c2[c], c2[c], sq); }
        const float mean = s * (1.f / C_DIM);
        const float var = sq * (1.f / C_DIM) - mean * mean;
        const float rs = rsqrtf(var + GN_EPS);
#pragma unroll
        for (int c = 0; c < C_DIM; c++)
            c2[c] = fmaf((c2[c] - mean) * rs, gng[c], gnb[c]);
    }
#pragma unroll
    for (int c = 0; c < C_DIM; c++) uacc[c] = bf[c];
#pragma unroll
    for (int q = 0; q < C_DIM / 4; q++) {
        const float4 g = ((const float4*)grow)[q];
        const float gs[4] = {g.x, g.y, g.z, g.w};
#pragma unroll
        for (int jj = 0; jj < 4; jj++) {
            const float gk = gs[jj];
            const int kk = 4 * q + jj;
#pragma unroll
            for (int c = 0; c < C_DIM; c++)
                uacc[c] = fmaf(gk, Wf[kk * C_DIM + c], uacc[c]);
        }
    }
#pragma unroll
    for (int kk = 0; kk < C_DIM; kk++) {
        const float ck = c2[kk];
#pragma unroll
        for (int c = 0; c < C_DIM; c++)
            uacc[c] = fmaf(ck, Wf[(C_DIM + kk) * C_DIM + c], uacc[c]);
    }
    {
        float s = 0.f, sq = 0.f;
#pragma unroll
        for (int c = 0; c < C_DIM; c++) { s += uacc[c]; sq = fmaf(uacc[c], uacc[c], sq); }
        const float mean = s * (1.f / C_DIM);
        const float var = sq * (1.f / C_DIM) - mean * mean;
        const float rs = rsqrtf(var + GN_EPS);
#pragma unroll
        for (int q = 0; q < C_DIM / 4; q++) {
            float4 o;
            o.x = leaky(fmaf((uacc[4*q+0] - mean) * rs, gfg[4*q+0], gfb[4*q+0]));
            o.y = leaky(fmaf((uacc[4*q+1] - mean) * rs, gfg[4*q+1], gfb[4*q+1]));
            o.z = leaky(fmaf((uacc[4*q+2] - mean) * rs, gfg[4*q+2], gfb[4*q+2]));
            o.w = leaky(fmaf((uacc[4*q+3] - mean) * rs, gfg[4*q+3], gfb[4*q+3]));
            ((float4*)orow)[q] = o;
        }
    }
}

extern "C" void kernel_launch(void* const* d_in, const int* in_sizes, int n_in,
                              void* d_out, int out_size, void* d_ws, size_t ws_size,
                              hipStream_t stream) {
    const float* gf     = (const float*)d_in[0];
    const float* pos    = (const float*)d_in[1];
    const int*   edge   = (const int*)d_in[2];
    const float* weight = (const float*)d_in[3];
    const float* W1  = (const float*)d_in[4];
    const float* b1  = (const float*)d_in[5];
    const float* W2  = (const float*)d_in[6];
    const float* b2  = (const float*)d_in[7];
    const float* gdg = (const float*)d_in[8];
    const float* gdb = (const float*)d_in[9];
    const float* Wa  = (const float*)d_in[10];
    const float* ba  = (const float*)d_in[11];
    const float* gng = (const float*)d_in[12];
    const float* gnb = (const float*)d_in[13];
    const float* Wf  = (const float*)d_in[14];
    const float* bf  = (const float*)d_in[15];
    const float* gfg = (const float*)d_in[16];
    const float* gfb = (const float*)d_in[17];

    float* out = (float*)d_out;
    const int E = in_sizes[3];
    const int N = in_sizes[0] / C_DIM;

    const size_t cnt_bytes  = (size_t)NSUC * sizeof(int);
    const size_t bidx_bytes = (size_t)NSUC * CAP * sizeof(int);
    const size_t stat_bytes = (size_t)E * sizeof(float2);
    dim3 blk(256);

    if (ws_size >= cnt_bytes + bidx_bytes + stat_bytes) {
        int* cnt  = (int*)d_ws;
        int* bidx = cnt + NSUC;
        float2* stats = (float2*)(bidx + (size_t)NSUC * CAP);
        hipMemsetAsync(cnt, 0, cnt_bytes, stream);
        bin_stats_kernel<<<dim3((E + 255) / 256), blk, 0, stream>>>(
            edge, pos, W1, b1, W2, b2, cnt, bidx, stats, E);
        node_lin_kernel<<<dim3((N + 255) / 256), blk, 0, stream>>>(
            gf, pos, edge, weight, W1, b1, W2, b2, gdg, gdb, Wa, ba,
            gng, gnb, Wf, bf, gfg, gfb, cnt, bidx, stats, out, N);
    } else {
        // R9 CSR fallback (proven to fit: 32.44 MB)
        int* cnt  = (int*)d_ws;
        int* bidx = cnt + NSUC;
        hipMemsetAsync(cnt, 0, cnt_bytes, stream);
        bin_kernel<<<dim3((E + 255) / 256), blk, 0, stream>>>(edge, cnt, bidx, E);
        node_csr_kernel<<<dim3((N + 255) / 256), blk, 0, stream>>>(
            gf, pos, edge, weight, W1, b1, W2, b2, gdg, gdb, Wa, ba,
            gng, gnb, Wf, bf, gfg, gfb, cnt, bidx, out, N);
    }
}

// Round 13
// 845.780 us; speedup vs baseline: 4.4730x; 1.4715x over previous
//
#include <hip/hip_runtime.h>

#define B_DIM 4
#define T_DIM 16
#define HW_DIM 4096
#define C_DIM 64
#define GN_EPS 1e-5f
#define NSUC (B_DIM * (T_DIM - 1) * HW_DIM)  // 245760 successor slots

__device__ __forceinline__ float leaky(float x) { return x > 0.f ? x : 0.01f * x; }

// select component j (compile-time) of a float4
#define HSEL(v4, j) ((j) == 0 ? (v4).x : (j) == 1 ? (v4).y : (j) == 2 ? (v4).z : (v4).w)

// ---------------- pass 1: count edges per successor node ----------------
__global__ __launch_bounds__(256, 8) void count_kernel(
    const int* __restrict__ edge, int* __restrict__ cnt, int E)
{
    int e = blockIdx.x * blockDim.x + threadIdx.x;
    if (e >= E) return;
    const int4 ev = ((const int4*)edge)[e];
    const int sc = (ev.x * (T_DIM - 1) + ev.y) * HW_DIM + ev.w;
    atomicAdd(&cnt[sc], 1);
}

// ---------------- pass 2: exclusive offsets (wave scan + 1 atomic/wave) ----------------
__global__ __launch_bounds__(256, 8) void offset_kernel(
    const int* __restrict__ cnt, int* __restrict__ off, int* __restrict__ cursor, int n)
{
    int i = blockIdx.x * blockDim.x + threadIdx.x;
    int c = (i < n) ? cnt[i] : 0;
    const int lane = threadIdx.x & 63;
    int pre = c;
#pragma unroll
    for (int d = 1; d < 64; d <<= 1) {
        int t = __shfl_up(pre, d);
        if (lane >= d) pre += t;
    }
    int tot = __shfl(pre, 63);
    int base = 0;
    if (lane == 63) base = atomicAdd(cursor, tot);
    base = __shfl(base, 63);
    if (i < n) off[i] = base + pre - c;
}

// ---------------- pass 3: per-edge GN stats + payload fill (edge-per-lane) ----------------
// h folded on the fly: only d[64] is live -> no spill at VGPR cap 128.
// payload: pay4 {pd0, pd1, w*rs, w}, pay2 {w*rs*mean, fp_bits}
__global__ __launch_bounds__(256, 4) void stats_fill_kernel(
    const int* __restrict__ edge, const float* __restrict__ pos,
    const float* __restrict__ weight,
    const float* __restrict__ W1, const float* __restrict__ b1,
    const float* __restrict__ W2, const float* __restrict__ b2,
    const int* __restrict__ off, int* __restrict__ fill,
    float4* __restrict__ pay4, float2* __restrict__ pay2, int E)
{
    int e = blockIdx.x * blockDim.x + threadIdx.x;
    if (e >= E) return;
    const int4 ev = ((const int4*)edge)[e];
    const int sc = (ev.x * (T_DIM - 1) + ev.y) * HW_DIM + ev.w;

    const float2 pp = ((const float2*)pos)[ev.y * HW_DIM + ev.z];
    const float2 ps = ((const float2*)pos)[(ev.y + 1) * HW_DIM + ev.w];
    const float pd0 = ps.x - pp.x;
    const float pd1 = ps.y - pp.y;

    float d[C_DIM];
#pragma unroll
    for (int c = 0; c < C_DIM; c++) d[c] = b2[c];
#pragma unroll
    for (int kk = 0; kk < C_DIM; kk++) {
        const float hv = leaky(fmaf(pd0, W1[kk], fmaf(pd1, W1[C_DIM + kk], b1[kk])));
#pragma unroll
        for (int c = 0; c < C_DIM; c++) d[c] = fmaf(hv, W2[kk * C_DIM + c], d[c]);
    }
    float s = 0.f, sq = 0.f;
#pragma unroll
    for (int c = 0; c < C_DIM; c++) { s += d[c]; sq = fmaf(d[c], d[c], sq); }
    const float mean = s * (1.f / C_DIM);
    const float var = sq * (1.f / C_DIM) - mean * mean;
    const float rsv = rsqrtf(var + GN_EPS);

    const float w = weight[e];
    const float wrs = w * rsv;
    const int fp = (ev.x * T_DIM + ev.y) * HW_DIM + ev.z;

    const int slot = atomicAdd(&fill[sc], 1);
    const int idx = off[sc] + slot;
    pay4[idx] = make_float4(pd0, pd1, wrs, w);
    pay2[idx] = make_float2(wrs * mean, __int_as_float(fp));
}

// ---------------- pass 4: node kernel, 16 lanes per node (4 channels/lane) ----------------
__global__ __launch_bounds__(256, 4) void node16_kernel(
    const float* __restrict__ gf,
    const float* __restrict__ W1, const float* __restrict__ b1,
    const float* __restrict__ W2, const float* __restrict__ b2,
    const float* __restrict__ gdg, const float* __restrict__ gdb,
    const float* __restrict__ Wa, const float* __restrict__ ba,
    const float* __restrict__ gng, const float* __restrict__ gnb,
    const float* __restrict__ Wf, const float* __restrict__ bf,
    const float* __restrict__ gfg, const float* __restrict__ gfb,
    const int* __restrict__ cnt, const int* __restrict__ off,
    const float4* __restrict__ pay4, const float2* __restrict__ pay2,
    float* __restrict__ out, int N)
{
    const int tid = blockIdx.x * blockDim.x + threadIdx.x;
    const int n = tid >> 4;
    if (n >= N) return;
    const int lig = tid & 15;             // lane-in-group, owns channels [4*lig, 4*lig+4)
    const int wl = threadIdx.x & 63;      // wave lane
    const int gb = wl & 48;               // group base within wave (16-lane groups)
    const int cb = 4 * lig;

    const float4 g = *(const float4*)(gf + (long)n * C_DIM + cb);
    float* orow = out + (long)n * C_DIM + cb;

    const int t = (n >> 12) & (T_DIM - 1);
    int k = 0, sc = 0;
    if (t > 0) {
        const int b = n >> 16;
        sc = n - (b + 1) * HW_DIM;
        k = cnt[sc];
    }
    if (k == 0) { *(float4*)orow = g; return; }

    const int base = off[sc];
    const float4 w1a = *(const float4*)(W1 + cb);
    const float4 w1b = *(const float4*)(W1 + C_DIM + cb);
    const float4 b1v = *(const float4*)(b1 + cb);

    float4 hacc = make_float4(0.f, 0.f, 0.f, 0.f);
    float4 vacc = make_float4(0.f, 0.f, 0.f, 0.f);
    float sw = 0.f, srs = 0.f, srm = 0.f;

    for (int j = 0; j < k; j++) {
        const float4 p = pay4[base + j];          // {pd0, pd1, wrs, w} broadcast in group
        const float2 q = pay2[base + j];          // {wrsm, fp}
        const int fp = __float_as_int(q.y);

        float4 hv;
        hv.x = leaky(fmaf(p.x, w1a.x, fmaf(p.y, w1b.x, b1v.x)));
        hv.y = leaky(fmaf(p.x, w1a.y, fmaf(p.y, w1b.y, b1v.y)));
        hv.z = leaky(fmaf(p.x, w1a.z, fmaf(p.y, w1b.z, b1v.z)));
        hv.w = leaky(fmaf(p.x, w1a.w, fmaf(p.y, w1b.w, b1v.w)));
        hacc.x = fmaf(p.z, hv.x, hacc.x);
        hacc.y = fmaf(p.z, hv.y, hacc.y);
        hacc.z = fmaf(p.z, hv.z, hacc.z);
        hacc.w = fmaf(p.z, hv.w, hacc.w);

        const float4 v = *(const float4*)(gf + (long)fp * C_DIM + cb);  // coalesced 256B/group
        vacc.x = fmaf(p.w, v.x, vacc.x);
        vacc.y = fmaf(p.w, v.y, vacc.y);
        vacc.z = fmaf(p.w, v.z, vacc.z);
        vacc.w = fmaf(p.w, v.w, vacc.w);

        sw += p.w; srs += p.z; srm += q.x;
    }

    // GEMV pass macro: acc += src_full[kk] * W[kk][c] for this lane's 4 channels
#define GEMV_PASS(src4, Wbase, acc)                                          \
    _Pragma("unroll")                                                        \
    for (int kk = 0; kk < C_DIM; kk++) {                                     \
        const float m_ = __shfl(HSEL(src4, kk & 3), gb + (kk >> 2));         \
        const float4 wv_ = *(const float4*)((Wbase) + kk * C_DIM + cb);      \
        acc.x = fmaf(m_, wv_.x, acc.x);                                      \
        acc.y = fmaf(m_, wv_.y, acc.y);                                      \
        acc.z = fmaf(m_, wv_.z, acc.z);                                      \
        acc.w = fmaf(m_, wv_.w, acc.w);                                      \
    }

    // t1 = hacc_full @ W2
    float4 t1 = make_float4(0.f, 0.f, 0.f, 0.f);
    GEMV_PASS(hacc, W2, t1)

    // uaccS = vacc + gdg*(t1 + srs*b2 - srm) + sw*gdb
    const float4 b2v = *(const float4*)(b2 + cb);
    const float4 gdgv = *(const float4*)(gdg + cb);
    const float4 gdbv = *(const float4*)(gdb + cb);
    float4 u;
    u.x = fmaf(gdgv.x, fmaf(srs, b2v.x, t1.x - srm), fmaf(sw, gdbv.x, vacc.x));
    u.y = fmaf(gdgv.y, fmaf(srs, b2v.y, t1.y - srm), fmaf(sw, gdbv.y, vacc.y));
    u.z = fmaf(gdgv.z, fmaf(srs, b2v.z, t1.z - srm), fmaf(sw, gdbv.z, vacc.z));
    u.w = fmaf(gdgv.w, fmaf(srs, b2v.w, t1.w - srm), fmaf(sw, gdbv.w, vacc.w));

    // c2 = u_full @ Wa + sw*ba
    const float4 bav = *(const float4*)(ba + cb);
    float4 c2 = make_float4(sw * bav.x, sw * bav.y, sw * bav.z, sw * bav.w);
    GEMV_PASS(u, Wa, c2)

    // GN(c2) over the 16-lane group
    float s = c2.x + c2.y + c2.z + c2.w;
    float sq = fmaf(c2.x, c2.x, fmaf(c2.y, c2.y, fmaf(c2.z, c2.z, c2.w * c2.w)));
#pragma unroll
    for (int m = 1; m < 16; m <<= 1) {
        s += __shfl_xor(s, m, 16);
        sq += __shfl_xor(sq, m, 16);
    }
    float mean = s * (1.f / C_DIM);
    float var = sq * (1.f / C_DIM) - mean * mean;
    float rs = rsqrtf(var + GN_EPS);
    const float4 gngv = *(const float4*)(gng + cb);
    const float4 gnbv = *(const float4*)(gnb + cb);
    float4 c2n;
    c2n.x = fmaf((c2.x - mean) * rs, gngv.x, gnbv.x);
    c2n.y = fmaf((c2.y - mean) * rs, gngv.y, gnbv.y);
    c2n.z = fmaf((c2.z - mean) * rs, gngv.z, gnbv.z);
    c2n.w = fmaf((c2.w - mean) * rs, gngv.w, gnbv.w);

    // d2 = bf + g_full @ Wf[0:64] + c2n_full @ Wf[64:128]
    const float4 bfv = *(const float4*)(bf + cb);
    float4 d2 = bfv;
    GEMV_PASS(g, Wf, d2)
    GEMV_PASS(c2n, Wf + C_DIM * C_DIM, d2)

    // final GN + leaky
    s = d2.x + d2.y + d2.z + d2.w;
    sq = fmaf(d2.x, d2.x, fmaf(d2.y, d2.y, fmaf(d2.z, d2.z, d2.w * d2.w)));
#pragma unroll
    for (int m = 1; m < 16; m <<= 1) {
        s += __shfl_xor(s, m, 16);
        sq += __shfl_xor(sq, m, 16);
    }
    mean = s * (1.f / C_DIM);
    var = sq * (1.f / C_DIM) - mean * mean;
    rs = rsqrtf(var + GN_EPS);
    const float4 gfgv = *(const float4*)(gfg + cb);
    const float4 gfbv = *(const float4*)(gfb + cb);
    float4 o;
    o.x = leaky(fmaf((d2.x - mean) * rs, gfgv.x, gfbv.x));
    o.y = leaky(fmaf((d2.y - mean) * rs, gfgv.y, gfbv.y));
    o.z = leaky(fmaf((d2.z - mean) * rs, gfgv.z, gfbv.z));
    o.w = leaky(fmaf((d2.w - mean) * rs, gfgv.w, gfbv.w));
    *(float4*)orow = o;
#undef GEMV_PASS
}

extern "C" void kernel_launch(void* const* d_in, const int* in_sizes, int n_in,
                              void* d_out, int out_size, void* d_ws, size_t ws_size,
                              hipStream_t stream) {
    const float* gf     = (const float*)d_in[0];
    const float* pos    = (const float*)d_in[1];
    const int*   edge   = (const int*)d_in[2];
    const float* weight = (const float*)d_in[3];
    const float* W1  = (const float*)d_in[4];
    const float* b1  = (const float*)d_in[5];
    const float* W2  = (const float*)d_in[6];
    const float* b2  = (const float*)d_in[7];
    const float* gdg = (const float*)d_in[8];
    const float* gdb = (const float*)d_in[9];
    const float* Wa  = (const float*)d_in[10];
    const float* ba  = (const float*)d_in[11];
    const float* gng = (const float*)d_in[12];
    const float* gnb = (const float*)d_in[13];
    const float* Wf  = (const float*)d_in[14];
    const float* bf  = (const float*)d_in[15];
    const float* gfg = (const float*)d_in[16];
    const float* gfb = (const float*)d_in[17];

    float* out = (float*)d_out;
    const int E = in_sizes[3];
    const int N = in_sizes[0] / C_DIM;

    // ws layout: [cursor 16B][cnt NSUC][fill NSUC][off NSUC][pay4 E*16][pay2 E*8]
    char* p = (char*)d_ws;
    int* cursor = (int*)p;
    int* cnt  = (int*)(p + 16);
    int* fill = (int*)(p + 16 + (size_t)NSUC * 4);
    int* off  = (int*)(p + 16 + (size_t)NSUC * 8);
    float4* pay4 = (float4*)(p + 16 + (size_t)NSUC * 12);
    float2* pay2 = (float2*)((char*)pay4 + (size_t)E * 16);

    // zero cursor + cnt + fill in one shot
    hipMemsetAsync(d_ws, 0, 16 + (size_t)NSUC * 8, stream);

    dim3 blk(256);
    count_kernel<<<dim3((E + 255) / 256), blk, 0, stream>>>(edge, cnt, E);
    offset_kernel<<<dim3((NSUC + 255) / 256), blk, 0, stream>>>(cnt, off, cursor, NSUC);
    stats_fill_kernel<<<dim3((E + 255) / 256), blk, 0, stream>>>(
        edge, pos, weight, W1, b1, W2, b2, off, fill, pay4, pay2, E);
    node16_kernel<<<dim3(((size_t)N * 16 + 255) / 256), blk, 0, stream>>>(
        gf, W1, b1, W2, b2, gdg, gdb, Wa, ba, gng, gnb, Wf, bf, gfg, gfb,
        cnt, off, pay4, pay2, out, N);
}